// Round 3
// baseline (487.594 us; speedup 1.0000x reference)
//
#include <hip/hip_runtime.h>

typedef unsigned short u16;
typedef unsigned int u32;
typedef u16 u16x4 __attribute__((ext_vector_type(4)));
typedef u16 u16x8 __attribute__((ext_vector_type(8)));
typedef float f32x4 __attribute__((ext_vector_type(4)));
typedef __bf16 bf16x8 __attribute__((ext_vector_type(8)));

// fp32 -> bf16 round-to-nearest-even
__device__ __forceinline__ u16 f2b(float f) {
  u32 u = __builtin_bit_cast(u32, f);
  u = (u + 0x7fffu + ((u >> 16) & 1u)) >> 16;
  return (u16)u;
}

__device__ __forceinline__ f32x4 mfma_bf16(u16x8 a, u16x8 b, f32x4 c) {
  return __builtin_amdgcn_mfma_f32_16x16x32_bf16(
      __builtin_bit_cast(bf16x8, a), __builtin_bit_cast(bf16x8, b), c, 0, 0, 0);
}

// ---------------- RoPE cos/sin table: [2048][32] each ----------------
__global__ void rope_tab_kernel(float* __restrict__ cost, float* __restrict__ sint) {
  int idx = blockIdx.x * 256 + threadIdx.x;   // 2048*32 = 65536
  int s = idx >> 5, j = idx & 31;
  float inv = expf(-(float)(2 * j) * (9.210340371976184f / 64.0f));
  float f = (float)s * inv;
  float sv, cv;
  sincosf(f, &sv, &cv);
  cost[idx] = cv;
  sint[idx] = sv;
}

// ---------------- GEMM: C[M,N] = A[M,K](f32) @ W[K,N](f32) + bias ----------------
// EPI 0: out = float*, row-major [M][N]
// EPI 1: out = bf16 head-major [B*NH][S][HD]  (V path)
// EPI 2: same as 1 but with fused RoPE        (Q/K paths)
template <int EPI>
__global__ __launch_bounds__(256) void gemm128(
    const float* __restrict__ A, const float* __restrict__ W,
    const float* __restrict__ bias, void* __restrict__ out,
    const float* __restrict__ cost, const float* __restrict__ sint,
    int M, int N, int K) {
  __shared__ u16 a_sh[128][40];   // [row][k]
  __shared__ u16 b_sh[128][40];   // [n][k]  (W transposed)

  const int t = threadIdx.x;
  const int m0 = blockIdx.x * 128, n0 = blockIdx.y * 128;
  const int w = t >> 6, lane = t & 63;
  const int wr = (w >> 1) * 64, wc = (w & 1) * 64;
  const int l15 = lane & 15, l16 = lane >> 4;

  f32x4 acc[4][4] = {};

  for (int k0 = 0; k0 < K; k0 += 32) {
    if (k0) __syncthreads();
#pragma unroll
    for (int it = 0; it < 4; ++it) {
      int i = t + it * 256;
      int r = i >> 3, c = (i & 7) * 4;
      float4 av = *(const float4*)(A + (size_t)(m0 + r) * K + k0 + c);
      u16x4 s4 = {f2b(av.x), f2b(av.y), f2b(av.z), f2b(av.w)};
      *(u16x4*)&a_sh[r][c] = s4;
    }
#pragma unroll
    for (int it = 0; it < 4; ++it) {
      int i = t + it * 256;
      int kr = i >> 5, nc = (i & 31) * 4;
      float4 wv = *(const float4*)(W + (size_t)(k0 + kr) * N + n0 + nc);
      b_sh[nc + 0][kr] = f2b(wv.x);
      b_sh[nc + 1][kr] = f2b(wv.y);
      b_sh[nc + 2][kr] = f2b(wv.z);
      b_sh[nc + 3][kr] = f2b(wv.w);
    }
    __syncthreads();

    u16x8 afr[4], bfr[4];
#pragma unroll
    for (int m = 0; m < 4; ++m) afr[m] = *(const u16x8*)&a_sh[wr + m * 16 + l15][l16 * 8];
#pragma unroll
    for (int n = 0; n < 4; ++n) bfr[n] = *(const u16x8*)&b_sh[wc + n * 16 + l15][l16 * 8];
#pragma unroll
    for (int m = 0; m < 4; ++m)
#pragma unroll
      for (int n = 0; n < 4; ++n) acc[m][n] = mfma_bf16(afr[m], bfr[n], acc[m][n]);
  }

  float bv[4];
#pragma unroll
  for (int n = 0; n < 4; ++n) bv[n] = bias[n0 + wc + n * 16 + l15];

#pragma unroll
  for (int m = 0; m < 4; ++m) {
#pragma unroll
    for (int i = 0; i < 4; ++i) {
      int row = m0 + wr + m * 16 + l16 * 4 + i;
#pragma unroll
      for (int n = 0; n < 4; ++n) {
        int col = n0 + wc + n * 16 + l15;
        float v = acc[m][n][i] + bv[n];
        if constexpr (EPI == 0) {
          ((float*)out)[(size_t)row * N + col] = v;
        } else {
          int b = row >> 11, s = row & 2047;
          int h = col >> 6, d = col & 63;
          float o = v;
          if constexpr (EPI == 2) {
            float partner = acc[m][n ^ 2][i] + bv[n ^ 2];
            float rot = (d < 32) ? -partner : partner;  // rotate_half
            float cs = cost[s * 32 + (d & 31)];
            float sn = sint[s * 32 + (d & 31)];
            o = v * cs + rot * sn;
          }
          ((u16*)out)[(((size_t)(b * 16 + h)) * 2048 + s) * 64 + d] = f2b(o);
        }
      }
    }
  }
}

// ---------------- flash attention, causal ----------------
__global__ __launch_bounds__(256) void attn_kernel(
    const u16* __restrict__ qh, const u16* __restrict__ kh, const u16* __restrict__ vh,
    const float* __restrict__ amask, float* __restrict__ ctx) {
  __shared__ u16 q_sh[128][72];
  __shared__ u16 k_sh[64][72];
  __shared__ u16 vt_sh[64][72];   // [d][kv]
  __shared__ u16 p_sh[128][72];

  const int t = threadIdx.x;
  const int qt = blockIdx.x, bh = blockIdx.y;
  const int b = bh >> 4, h = bh & 15;
  const int q0 = qt * 128;
  const int w = t >> 6, lane = t & 63;
  const int l15 = lane & 15, l16 = lane >> 4;
  const int wq = w * 32;

#pragma unroll
  for (int it = 0; it < 4; ++it) {
    int i = t + it * 256;
    int r = i >> 3, c = (i & 7) * 8;
    *(u16x8*)&q_sh[r][c] = *(const u16x8*)(qh + ((size_t)bh * 2048 + q0 + r) * 64 + c);
  }

  f32x4 o_acc[2][4] = {};
  float mrun[2][4], lrun[2][4];
#pragma unroll
  for (int m = 0; m < 2; ++m)
#pragma unroll
    for (int i = 0; i < 4; ++i) { mrun[m][i] = -1e30f; lrun[m][i] = 0.f; }

  const int nkt = 2 * qt + 2;  // causal tile bound
  for (int kt = 0; kt < nkt; ++kt) {
    const int k0 = kt * 64;
    __syncthreads();
#pragma unroll
    for (int it = 0; it < 2; ++it) {
      int i = t + it * 256;
      int r = i >> 3, c = (i & 7) * 8;
      *(u16x8*)&k_sh[r][c] = *(const u16x8*)(kh + ((size_t)bh * 2048 + k0 + r) * 64 + c);
      u16x8 vv = *(const u16x8*)(vh + ((size_t)bh * 2048 + k0 + r) * 64 + c);
#pragma unroll
      for (int e = 0; e < 8; ++e) vt_sh[c + e][r] = vv[e];
    }
    __syncthreads();

    f32x4 sa[2][4] = {};
#pragma unroll
    for (int ks = 0; ks < 2; ++ks) {
      u16x8 af[2], bf[4];
#pragma unroll
      for (int m = 0; m < 2; ++m) af[m] = *(const u16x8*)&q_sh[wq + m * 16 + l15][ks * 32 + l16 * 8];
#pragma unroll
      for (int n = 0; n < 4; ++n) bf[n] = *(const u16x8*)&k_sh[n * 16 + l15][ks * 32 + l16 * 8];
#pragma unroll
      for (int m = 0; m < 2; ++m)
#pragma unroll
        for (int n = 0; n < 4; ++n) sa[m][n] = mfma_bf16(af[m], bf[n], sa[m][n]);
    }

    // online softmax (rows replicated across each 16-lane group)
#pragma unroll
    for (int m = 0; m < 2; ++m) {
#pragma unroll
      for (int i = 0; i < 4; ++i) {
        int qrow = q0 + wq + m * 16 + l16 * 4 + i;
        float vals[4];
        float tmax = -1e30f;
#pragma unroll
        for (int n = 0; n < 4; ++n) {
          int kcol = k0 + n * 16 + l15;
          float s = sa[m][n][i] * 0.125f + (1.0f - amask[b * 2048 + kcol]) * -1e4f;
          if (kcol > qrow) s = -1e10f;
          vals[n] = s;
          tmax = fmaxf(tmax, s);
        }
#pragma unroll
        for (int off = 1; off < 16; off <<= 1) tmax = fmaxf(tmax, __shfl_xor(tmax, off));
        float mnew = fmaxf(mrun[m][i], tmax);
        float alpha = __expf(mrun[m][i] - mnew);
        float psum = 0.f;
#pragma unroll
        for (int n = 0; n < 4; ++n) {
          float p = __expf(vals[n] - mnew);
          psum += p;
          p_sh[wq + m * 16 + l16 * 4 + i][n * 16 + l15] = f2b(p);
        }
#pragma unroll
        for (int off = 1; off < 16; off <<= 1) psum += __shfl_xor(psum, off);
        lrun[m][i] = lrun[m][i] * alpha + psum;
        mrun[m][i] = mnew;
        // FIX (R1): rescale ONLY row i's accumulator component — o_acc[m][n] is
        // an f32x4 over 4 q-rows; scaling the whole vector applied
        // alpha_0*alpha_1*alpha_2*alpha_3 to every row (absmax 0.27 bug).
#pragma unroll
        for (int n = 0; n < 4; ++n) o_acc[m][n][i] *= alpha;
      }
    }

    // O += P @ V   (P rows are wave-private; no barrier needed)
#pragma unroll
    for (int ks = 0; ks < 2; ++ks) {
      u16x8 pf[2], vf[4];
#pragma unroll
      for (int m = 0; m < 2; ++m) pf[m] = *(const u16x8*)&p_sh[wq + m * 16 + l15][ks * 32 + l16 * 8];
#pragma unroll
      for (int n = 0; n < 4; ++n) vf[n] = *(const u16x8*)&vt_sh[n * 16 + l15][ks * 32 + l16 * 8];
#pragma unroll
      for (int m = 0; m < 2; ++m)
#pragma unroll
        for (int n = 0; n < 4; ++n) o_acc[m][n] = mfma_bf16(pf[m], vf[n], o_acc[m][n]);
    }
  }

#pragma unroll
  for (int m = 0; m < 2; ++m) {
#pragma unroll
    for (int i = 0; i < 4; ++i) {
      float inv = 1.0f / lrun[m][i];
      int s = q0 + wq + m * 16 + l16 * 4 + i;
#pragma unroll
      for (int n = 0; n < 4; ++n) {
        int d = n * 16 + l15;
        ctx[((size_t)(b * 2048 + s)) * 1024 + h * 64 + d] = o_acc[m][n][i] * inv;
      }
    }
  }
}

extern "C" void kernel_launch(void* const* d_in, const int* in_sizes, int n_in,
                              void* d_out, int out_size, void* d_ws, size_t ws_size,
                              hipStream_t stream) {
  const float* hs = (const float*)d_in[0];
  const float* amask = (const float*)d_in[1];
  const float* Wq = (const float*)d_in[2];
  const float* bq = (const float*)d_in[3];
  const float* Wk = (const float*)d_in[4];
  const float* bk = (const float*)d_in[5];
  const float* Wv = (const float*)d_in[6];
  const float* bv = (const float*)d_in[7];
  const float* Wo = (const float*)d_in[8];
  const float* bo = (const float*)d_in[9];
  float* out = (float*)d_out;

  char* ws = (char*)d_ws;
  float* cost = (float*)ws;                       // 2048*32 f32
  float* sint = cost + 2048 * 32;                 // 2048*32 f32
  u16* qh = (u16*)(sint + 2048 * 32);             // 32*2048*64 bf16
  u16* kh = qh + 32 * 2048 * 64;
  u16* vh = kh + 32 * 2048 * 64;
  float* ctx = (float*)(vh + 32 * 2048 * 64);     // 4096*1024 f32

  rope_tab_kernel<<<256, 256, 0, stream>>>(cost, sint);

  dim3 gg(32, 8);
  gemm128<2><<<gg, 256, 0, stream>>>(hs, Wq, bq, qh, cost, sint, 4096, 1024, 1024);
  gemm128<2><<<gg, 256, 0, stream>>>(hs, Wk, bk, kh, cost, sint, 4096, 1024, 1024);
  gemm128<1><<<gg, 256, 0, stream>>>(hs, Wv, bv, vh, cost, sint, 4096, 1024, 1024);

  attn_kernel<<<dim3(16, 32), 256, 0, stream>>>(qh, kh, vh, amask, ctx);

  gemm128<0><<<gg, 256, 0, stream>>>(ctx, Wo, bo, out, nullptr, nullptr, 4096, 1024, 1024);
}

// Round 4
// 360.420 us; speedup vs baseline: 1.3528x; 1.3528x over previous
//
#include <hip/hip_runtime.h>

typedef unsigned short u16;
typedef unsigned int u32;
typedef u16 u16x4 __attribute__((ext_vector_type(4)));
typedef u16 u16x8 __attribute__((ext_vector_type(8)));
typedef float f32x4 __attribute__((ext_vector_type(4)));
typedef __bf16 bf16x8 __attribute__((ext_vector_type(8)));

// fp32 -> bf16 round-to-nearest-even
__device__ __forceinline__ u16 f2b(float f) {
  u32 u = __builtin_bit_cast(u32, f);
  u = (u + 0x7fffu + ((u >> 16) & 1u)) >> 16;
  return (u16)u;
}

__device__ __forceinline__ f32x4 mfma_bf16(u16x8 a, u16x8 b, f32x4 c) {
  return __builtin_amdgcn_mfma_f32_16x16x32_bf16(
      __builtin_bit_cast(bf16x8, a), __builtin_bit_cast(bf16x8, b), c, 0, 0, 0);
}

// async global->LDS, 16B per lane; lds ptr must be wave-uniform base
__device__ __forceinline__ void gload16(const u16* g, void* lds_base) {
  __builtin_amdgcn_global_load_lds(
      (const __attribute__((address_space(1))) void*)g,
      (__attribute__((address_space(3))) void*)lds_base, 16, 0, 0);
}

// ---------------- prep kernels ----------------
__global__ __launch_bounds__(256) void to_bf16_kernel(const float* __restrict__ in,
                                                      u16* __restrict__ out, int n4) {
  int i = blockIdx.x * 256 + threadIdx.x;
  if (i < n4) {
    float4 v = *(const float4*)(in + (size_t)i * 4);
    u16x4 o = {f2b(v.x), f2b(v.y), f2b(v.z), f2b(v.w)};
    *(u16x4*)(out + (size_t)i * 4) = o;
  }
}

// W f32 [1024][1024] -> Wt bf16 [n][k]
__global__ __launch_bounds__(256) void transpose_w_kernel(const float* __restrict__ W,
                                                          u16* __restrict__ Wt) {
  __shared__ u16 tl[64][68];
  const int r0 = blockIdx.x * 64, c0 = blockIdx.y * 64;
  const int t = threadIdx.x;
  const int ti = t >> 4, tj = (t & 15) * 4;
#pragma unroll
  for (int it = 0; it < 4; ++it) {
    int ki = ti + it * 16;
    float4 wv = *(const float4*)(W + (size_t)(r0 + ki) * 1024 + c0 + tj);
    tl[ki][tj + 0] = f2b(wv.x);
    tl[ki][tj + 1] = f2b(wv.y);
    tl[ki][tj + 2] = f2b(wv.z);
    tl[ki][tj + 3] = f2b(wv.w);
  }
  __syncthreads();
#pragma unroll
  for (int it = 0; it < 4; ++it) {
    int ni = ti + it * 16;
    u16x4 o = {tl[tj + 0][ni], tl[tj + 1][ni], tl[tj + 2][ni], tl[tj + 3][ni]};
    *(u16x4*)(Wt + (size_t)(c0 + ni) * 1024 + r0 + tj) = o;
  }
}

// ---------------- RoPE cos/sin table: [2048][32] each ----------------
__global__ void rope_tab_kernel(float* __restrict__ cost, float* __restrict__ sint) {
  int idx = blockIdx.x * 256 + threadIdx.x;  // 2048*32
  int s = idx >> 5, j = idx & 31;
  float inv = expf(-(float)(2 * j) * (9.210340371976184f / 64.0f));
  float f = (float)s * inv;
  float sv, cv;
  sincosf(f, &sv, &cv);
  cost[idx] = cv;
  sint[idx] = sv;
}

// ---------------- bf16 GEMM: C[M,N] = A[M,K] @ Bt[N,K]^T + bias ----------------
// m97 recipe: 128x128 tile, BK=64, global_load_lds w=16, XOR-swizzled LDS.
// EPI 0: fp32 row-major [M][N]
// EPI 2: bf16 head-major [BH][S][HD] + fused RoPE (Q/K)
// EPI 3: bf16 head-major TRANSPOSED [BH][HD][S] (V)
template <int EPI>
__global__ __launch_bounds__(256) void gemm_bf16(
    const u16* __restrict__ A, const u16* __restrict__ Bt,
    const float* __restrict__ bias, void* __restrict__ out,
    const float* __restrict__ cost, const float* __restrict__ sint,
    int M, int N, int K) {
  __shared__ u16 a_sh[128 * 64];
  __shared__ u16 b_sh[128 * 64];

  const int t = threadIdx.x;
  const int m0 = blockIdx.x * 128, n0 = blockIdx.y * 128;
  const int w = t >> 6, lane = t & 63;
  const int l15 = lane & 15, l16 = lane >> 4;
  const int wr = (w >> 1) * 64, wc = (w & 1) * 64;

  f32x4 acc[4][4] = {};

  for (int k0 = 0; k0 < K; k0 += 64) {
    if (k0) __syncthreads();
    // stage A and B tiles (128x64 bf16 each) via global_load_lds.
    // LDS layout linear [row][64]; source pre-swizzled so swizzled ds_read
    // (byte ^= (row&7)<<4) reads correct data bank-conflict-free (rule #21).
#pragma unroll
    for (int it = 0; it < 4; ++it) {
      int Lbase = it * 4096 + w * 1024;       // wave-uniform
      int L = Lbase + lane * 16;              // this lane's dest byte
      int r = L >> 7;
      int Ls = L ^ ((r & 7) << 4);
      int c = (Ls & 127) >> 1;                // element col in [0,64)
      gload16(A + (size_t)(m0 + r) * K + k0 + c, (char*)a_sh + Lbase);
      gload16(Bt + (size_t)(n0 + r) * K + k0 + c, (char*)b_sh + Lbase);
    }
    __syncthreads();

#pragma unroll
    for (int ks = 0; ks < 2; ++ks) {
      u16x8 af[4], bf[4];
#pragma unroll
      for (int m = 0; m < 4; ++m) {
        int row = wr + m * 16 + l15;
        int byt = ((row << 7) + ks * 64 + l16 * 16) ^ ((row & 7) << 4);
        af[m] = *(const u16x8*)((char*)a_sh + byt);
      }
#pragma unroll
      for (int n = 0; n < 4; ++n) {
        int row = wc + n * 16 + l15;
        int byt = ((row << 7) + ks * 64 + l16 * 16) ^ ((row & 7) << 4);
        bf[n] = *(const u16x8*)((char*)b_sh + byt);
      }
#pragma unroll
      for (int m = 0; m < 4; ++m)
#pragma unroll
        for (int n = 0; n < 4; ++n) acc[m][n] = mfma_bf16(af[m], bf[n], acc[m][n]);
    }
  }

  float bv[4];
#pragma unroll
  for (int n = 0; n < 4; ++n) bv[n] = bias[n0 + wc + n * 16 + l15];

  if constexpr (EPI == 3) {
    // V: vt[bh][d][s], vectorized over the 4 consecutive s of each acc vec
#pragma unroll
    for (int m = 0; m < 4; ++m) {
      int row0 = m0 + wr + m * 16 + l16 * 4;
      int b = row0 >> 11, s0 = row0 & 2047;
#pragma unroll
      for (int n = 0; n < 4; ++n) {
        int col = n0 + wc + n * 16 + l15;
        int h = col >> 6, d = col & 63;
        u16x4 pk = {f2b(acc[m][n][0] + bv[n]), f2b(acc[m][n][1] + bv[n]),
                    f2b(acc[m][n][2] + bv[n]), f2b(acc[m][n][3] + bv[n])};
        *(u16x4*)((u16*)out + ((size_t)((b * 16 + h) * 64 + d)) * 2048 + s0) = pk;
      }
    }
  } else {
#pragma unroll
    for (int m = 0; m < 4; ++m) {
#pragma unroll
      for (int i = 0; i < 4; ++i) {
        int row = m0 + wr + m * 16 + l16 * 4 + i;
#pragma unroll
        for (int n = 0; n < 4; ++n) {
          int col = n0 + wc + n * 16 + l15;
          float v = acc[m][n][i] + bv[n];
          if constexpr (EPI == 0) {
            ((float*)out)[(size_t)row * N + col] = v;
          } else {  // EPI == 2: RoPE + head-major bf16 [BH][S][HD]
            int b = row >> 11, s = row & 2047;
            int h = col >> 6, d = col & 63;
            float partner = acc[m][n ^ 2][i] + bv[n ^ 2];
            float rot = (d < 32) ? -partner : partner;  // rotate_half
            float cs = cost[s * 32 + (d & 31)];
            float sn = sint[s * 32 + (d & 31)];
            float o = v * cs + rot * sn;
            ((u16*)out)[(((size_t)(b * 16 + h)) * 2048 + s) * 64 + d] = f2b(o);
          }
        }
      }
    }
  }
}

// ---------------- flash attention, causal ----------------
// qh,kh: [BH][S][HD] bf16; vt: [BH][HD][S] bf16 (pre-transposed); ctx out bf16 [B][S][H]
__global__ __launch_bounds__(256) void attn_kernel(
    const u16* __restrict__ qh, const u16* __restrict__ kh, const u16* __restrict__ vt,
    const float* __restrict__ amask, u16* __restrict__ ctx) {
  __shared__ u16 q_sh[128][72];
  __shared__ u16 k_sh[64][72];
  __shared__ u16 vt_sh[64][72];   // [d][kv]
  __shared__ u16 p_sh[128][72];

  const int t = threadIdx.x;
  const int qt = (int)gridDim.x - 1 - (int)blockIdx.x;  // LPT: heavy tiles first
  const int bh = blockIdx.y;
  const int b = bh >> 4, h = bh & 15;
  const int q0 = qt * 128;
  const int w = t >> 6, lane = t & 63;
  const int l15 = lane & 15, l16 = lane >> 4;
  const int wq = w * 32;

#pragma unroll
  for (int it = 0; it < 4; ++it) {
    int i = t + it * 256;
    int r = i >> 3, c = (i & 7) * 8;
    *(u16x8*)&q_sh[r][c] = *(const u16x8*)(qh + ((size_t)bh * 2048 + q0 + r) * 64 + c);
  }

  f32x4 o_acc[2][4] = {};
  float mrun[2][4], lrun[2][4];
#pragma unroll
  for (int m = 0; m < 2; ++m)
#pragma unroll
    for (int i = 0; i < 4; ++i) { mrun[m][i] = -1e30f; lrun[m][i] = 0.f; }

  const int nkt = 2 * qt + 2;  // causal tile bound
  for (int kt = 0; kt < nkt; ++kt) {
    const int k0 = kt * 64;
    __syncthreads();
    // stage K rows [kv][d] and V^T rows [d][kv] — both straight vector copies
#pragma unroll
    for (int it = 0; it < 2; ++it) {
      int i = t + it * 256;
      int r = i >> 3, c = (i & 7) * 8;
      *(u16x8*)&k_sh[r][c] = *(const u16x8*)(kh + ((size_t)bh * 2048 + k0 + r) * 64 + c);
      *(u16x8*)&vt_sh[r][c] = *(const u16x8*)(vt + ((size_t)bh * 64 + r) * 2048 + k0 + c);
    }
    __syncthreads();

    f32x4 sa[2][4] = {};
#pragma unroll
    for (int ks = 0; ks < 2; ++ks) {
      u16x8 af[2], bf[4];
#pragma unroll
      for (int m = 0; m < 2; ++m) af[m] = *(const u16x8*)&q_sh[wq + m * 16 + l15][ks * 32 + l16 * 8];
#pragma unroll
      for (int n = 0; n < 4; ++n) bf[n] = *(const u16x8*)&k_sh[n * 16 + l15][ks * 32 + l16 * 8];
#pragma unroll
      for (int m = 0; m < 2; ++m)
#pragma unroll
        for (int n = 0; n < 4; ++n) sa[m][n] = mfma_bf16(af[m], bf[n], sa[m][n]);
    }

    // online softmax (rows replicated across each 16-lane group)
#pragma unroll
    for (int m = 0; m < 2; ++m) {
#pragma unroll
      for (int i = 0; i < 4; ++i) {
        int qrow = q0 + wq + m * 16 + l16 * 4 + i;
        float vals[4];
        float tmax = -1e30f;
#pragma unroll
        for (int n = 0; n < 4; ++n) {
          int kcol = k0 + n * 16 + l15;
          float s = sa[m][n][i] * 0.125f + (1.0f - amask[b * 2048 + kcol]) * -1e4f;
          if (kcol > qrow) s = -1e10f;
          vals[n] = s;
          tmax = fmaxf(tmax, s);
        }
#pragma unroll
        for (int off = 1; off < 16; off <<= 1) tmax = fmaxf(tmax, __shfl_xor(tmax, off));
        float mnew = fmaxf(mrun[m][i], tmax);
        float alpha = __expf(mrun[m][i] - mnew);
        float psum = 0.f;
#pragma unroll
        for (int n = 0; n < 4; ++n) {
          float p = __expf(vals[n] - mnew);
          psum += p;
          p_sh[wq + m * 16 + l16 * 4 + i][n * 16 + l15] = f2b(p);
        }
#pragma unroll
        for (int off = 1; off < 16; off <<= 1) psum += __shfl_xor(psum, off);
        lrun[m][i] = lrun[m][i] * alpha + psum;
        mrun[m][i] = mnew;
        // per-row rescale (R1 fix): only component i
#pragma unroll
        for (int n = 0; n < 4; ++n) o_acc[m][n][i] *= alpha;
      }
    }

    // O += P @ V (P rows wave-private; no barrier needed)
#pragma unroll
    for (int ks = 0; ks < 2; ++ks) {
      u16x8 pf[2], vf[4];
#pragma unroll
      for (int m = 0; m < 2; ++m) pf[m] = *(const u16x8*)&p_sh[wq + m * 16 + l15][ks * 32 + l16 * 8];
#pragma unroll
      for (int n = 0; n < 4; ++n) vf[n] = *(const u16x8*)&vt_sh[n * 16 + l15][ks * 32 + l16 * 8];
#pragma unroll
      for (int m = 0; m < 2; ++m)
#pragma unroll
        for (int n = 0; n < 4; ++n) o_acc[m][n] = mfma_bf16(pf[m], vf[n], o_acc[m][n]);
    }
  }

  // ctx bf16 [B][S][H]
#pragma unroll
  for (int m = 0; m < 2; ++m) {
#pragma unroll
    for (int i = 0; i < 4; ++i) {
      float inv = 1.0f / lrun[m][i];
      int s = q0 + wq + m * 16 + l16 * 4 + i;
#pragma unroll
      for (int n = 0; n < 4; ++n) {
        int d = n * 16 + l15;
        ctx[((size_t)(b * 2048 + s)) * 1024 + h * 64 + d] = f2b(o_acc[m][n][i] * inv);
      }
    }
  }
}

extern "C" void kernel_launch(void* const* d_in, const int* in_sizes, int n_in,
                              void* d_out, int out_size, void* d_ws, size_t ws_size,
                              hipStream_t stream) {
  const float* hs = (const float*)d_in[0];
  const float* amask = (const float*)d_in[1];
  const float* Wq = (const float*)d_in[2];
  const float* bq = (const float*)d_in[3];
  const float* Wk = (const float*)d_in[4];
  const float* bk = (const float*)d_in[5];
  const float* Wv = (const float*)d_in[6];
  const float* bv = (const float*)d_in[7];
  const float* Wo = (const float*)d_in[8];
  const float* bo = (const float*)d_in[9];
  float* out = (float*)d_out;

  // workspace layout (~40.75 MB)
  char* ws = (char*)d_ws;
  float* cost = (float*)ws;                        // 2048*32 f32
  float* sint = cost + 2048 * 32;
  u16* hsb = (u16*)(sint + 2048 * 32);             // 4096*1024 bf16 (reused as ctxb)
  u16* wqt = hsb + 4096 * 1024;                    // 1024*1024 bf16 each
  u16* wkt = wqt + 1024 * 1024;
  u16* wvt = wkt + 1024 * 1024;
  u16* wot = wvt + 1024 * 1024;
  u16* qh = wot + 1024 * 1024;                     // 32*2048*64 bf16 each
  u16* kh = qh + 32 * 2048 * 64;
  u16* vtg = kh + 32 * 2048 * 64;
  u16* ctxb = hsb;  // overlay: hsb dead after V-GEMM, attn writes ctxb after

  to_bf16_kernel<<<4096, 256, 0, stream>>>(hs, hsb, 1048576);
  dim3 tg(16, 16);
  transpose_w_kernel<<<tg, 256, 0, stream>>>(Wq, wqt);
  transpose_w_kernel<<<tg, 256, 0, stream>>>(Wk, wkt);
  transpose_w_kernel<<<tg, 256, 0, stream>>>(Wv, wvt);
  transpose_w_kernel<<<tg, 256, 0, stream>>>(Wo, wot);
  rope_tab_kernel<<<256, 256, 0, stream>>>(cost, sint);

  dim3 gg(32, 8);
  gemm_bf16<2><<<gg, 256, 0, stream>>>(hsb, wqt, bq, qh, cost, sint, 4096, 1024, 1024);
  gemm_bf16<2><<<gg, 256, 0, stream>>>(hsb, wkt, bk, kh, cost, sint, 4096, 1024, 1024);
  gemm_bf16<3><<<gg, 256, 0, stream>>>(hsb, wvt, bv, vtg, cost, sint, 4096, 1024, 1024);

  attn_kernel<<<dim3(16, 32), 256, 0, stream>>>(qh, kh, vtg, amask, ctxb);

  gemm_bf16<0><<<gg, 256, 0, stream>>>(ctxb, wot, bo, out, nullptr, nullptr, 4096, 1024, 1024);
}

// Round 5
// 275.631 us; speedup vs baseline: 1.7690x; 1.3076x over previous
//
#include <hip/hip_runtime.h>

typedef unsigned short u16;
typedef unsigned int u32;
typedef u16 u16x4 __attribute__((ext_vector_type(4)));
typedef u16 u16x8 __attribute__((ext_vector_type(8)));
typedef float f32x4 __attribute__((ext_vector_type(4)));
typedef __bf16 bf16x8 __attribute__((ext_vector_type(8)));

// fp32 -> bf16 round-to-nearest-even
__device__ __forceinline__ u16 f2b(float f) {
  u32 u = __builtin_bit_cast(u32, f);
  u = (u + 0x7fffu + ((u >> 16) & 1u)) >> 16;
  return (u16)u;
}

__device__ __forceinline__ f32x4 mfma_bf16(u16x8 a, u16x8 b, f32x4 c) {
  return __builtin_amdgcn_mfma_f32_16x16x32_bf16(
      __builtin_bit_cast(bf16x8, a), __builtin_bit_cast(bf16x8, b), c, 0, 0, 0);
}

// async global->LDS, 16B/lane; lds base wave-uniform, lane scatter = base+lane*16
__device__ __forceinline__ void gload16(const u16* g, void* lds_base) {
  __builtin_amdgcn_global_load_lds(
      (const __attribute__((address_space(1))) void*)g,
      (__attribute__((address_space(3))) void*)lds_base, 16, 0, 0);
}

// ---------------- prep kernels ----------------
__global__ __launch_bounds__(256) void to_bf16_kernel(const float* __restrict__ in,
                                                      u16* __restrict__ out, int n4) {
  int i = blockIdx.x * 256 + threadIdx.x;
  if (i < n4) {
    float4 v = *(const float4*)(in + (size_t)i * 4);
    u16x4 o = {f2b(v.x), f2b(v.y), f2b(v.z), f2b(v.w)};
    *(u16x4*)(out + (size_t)i * 4) = o;
  }
}

// W f32 [1024][1024] -> Wt bf16 [n][k]
__global__ __launch_bounds__(256) void transpose_w_kernel(const float* __restrict__ W,
                                                          u16* __restrict__ Wt) {
  __shared__ u16 tl[64][68];
  const int r0 = blockIdx.x * 64, c0 = blockIdx.y * 64;
  const int t = threadIdx.x;
  const int ti = t >> 4, tj = (t & 15) * 4;
#pragma unroll
  for (int it = 0; it < 4; ++it) {
    int ki = ti + it * 16;
    float4 wv = *(const float4*)(W + (size_t)(r0 + ki) * 1024 + c0 + tj);
    tl[ki][tj + 0] = f2b(wv.x);
    tl[ki][tj + 1] = f2b(wv.y);
    tl[ki][tj + 2] = f2b(wv.z);
    tl[ki][tj + 3] = f2b(wv.w);
  }
  __syncthreads();
#pragma unroll
  for (int it = 0; it < 4; ++it) {
    int ni = ti + it * 16;
    u16x4 o = {tl[tj + 0][ni], tl[tj + 1][ni], tl[tj + 2][ni], tl[tj + 3][ni]};
    *(u16x4*)(Wt + (size_t)(c0 + ni) * 1024 + r0 + tj) = o;
  }
}

// bias concat [bq|bk|bv] -> 3072
__global__ __launch_bounds__(256) void pack_bias_kernel(const float* __restrict__ bq,
                                                        const float* __restrict__ bk,
                                                        const float* __restrict__ bv,
                                                        float* __restrict__ o) {
  int i = blockIdx.x * 256 + threadIdx.x;  // 3072
  o[i] = (i < 1024) ? bq[i] : (i < 2048) ? bk[i - 1024] : bv[i - 2048];
}

// ---------------- RoPE cos/sin table ----------------
__global__ void rope_tab_kernel(float* __restrict__ cost, float* __restrict__ sint) {
  int idx = blockIdx.x * 256 + threadIdx.x;  // 2048*32
  int s = idx >> 5, j = idx & 31;
  float inv = expf(-(float)(2 * j) * (9.210340371976184f / 64.0f));
  float f = (float)s * inv;
  float sv, cv;
  sincosf(f, &sv, &cv);
  cost[idx] = cv;
  sint[idx] = sv;
}

// ---------------- bf16 GEMM: C[M,N] = A[M,K] @ Bt[N,K]^T + bias ----------------
// BMxBN=BMx128 tile, BK=64, global_load_lds w=16, both-sides XOR swizzle.
// EPI 0: fp32 row-major out0
// EPI 4: fused QKV (N=3072): proj0/1 -> RoPE head-major bf16 (out0=qh,out1=kh);
//        proj2 -> transposed head-major bf16 (out2=vt)
template <int EPI, int BM>
__global__ __launch_bounds__(256) void gemm_bf16(
    const u16* __restrict__ A, const u16* __restrict__ Bt,
    const float* __restrict__ bias, void* __restrict__ out0, void* __restrict__ out1,
    void* __restrict__ out2, const float* __restrict__ cost,
    const float* __restrict__ sint, int M, int N, int K) {
  constexpr int WM = BM / 2;    // rows per wave
  constexpr int MR = WM / 16;   // m-fragments per wave
  __shared__ u16 a_sh[BM * 64];
  __shared__ u16 b_sh[128 * 64];

  const int t = threadIdx.x;
  const int m0 = blockIdx.x * BM, n0 = blockIdx.y * 128;
  const int w = t >> 6, lane = t & 63;
  const int l15 = lane & 15, l16 = lane >> 4;
  const int wr = (w >> 1) * WM, wc = (w & 1) * 64;

  f32x4 acc[MR][4] = {};

  for (int k0 = 0; k0 < K; k0 += 64) {
    if (k0) __syncthreads();
#pragma unroll
    for (int it = 0; it < BM / 32; ++it) {
      int Lbase = it * 4096 + w * 1024;
      int L = Lbase + lane * 16;
      int r = L >> 7;
      int c = ((L ^ ((r & 7) << 4)) & 127) >> 1;
      gload16(A + (size_t)(m0 + r) * K + k0 + c, (char*)a_sh + Lbase);
    }
#pragma unroll
    for (int it = 0; it < 4; ++it) {
      int Lbase = it * 4096 + w * 1024;
      int L = Lbase + lane * 16;
      int r = L >> 7;
      int c = ((L ^ ((r & 7) << 4)) & 127) >> 1;
      gload16(Bt + (size_t)(n0 + r) * K + k0 + c, (char*)b_sh + Lbase);
    }
    __syncthreads();

#pragma unroll
    for (int ks = 0; ks < 2; ++ks) {
      u16x8 af[MR], bf[4];
#pragma unroll
      for (int m = 0; m < MR; ++m) {
        int row = wr + m * 16 + l15;
        int byt = ((row << 7) + ks * 64 + l16 * 16) ^ ((row & 7) << 4);
        af[m] = *(const u16x8*)((char*)a_sh + byt);
      }
#pragma unroll
      for (int n = 0; n < 4; ++n) {
        int row = wc + n * 16 + l15;
        int byt = ((row << 7) + ks * 64 + l16 * 16) ^ ((row & 7) << 4);
        bf[n] = *(const u16x8*)((char*)b_sh + byt);
      }
#pragma unroll
      for (int m = 0; m < MR; ++m)
#pragma unroll
        for (int n = 0; n < 4; ++n) acc[m][n] = mfma_bf16(af[m], bf[n], acc[m][n]);
    }
  }

  float bv[4];
#pragma unroll
  for (int n = 0; n < 4; ++n) bv[n] = bias[n0 + wc + n * 16 + l15];

  if constexpr (EPI == 0) {
#pragma unroll
    for (int m = 0; m < MR; ++m)
#pragma unroll
      for (int i = 0; i < 4; ++i) {
        int row = m0 + wr + m * 16 + l16 * 4 + i;
#pragma unroll
        for (int n = 0; n < 4; ++n) {
          int col = n0 + wc + n * 16 + l15;
          ((float*)out0)[(size_t)row * N + col] = acc[m][n][i] + bv[n];
        }
      }
  } else {  // EPI == 4
    int proj = n0 >> 10;  // uniform per block
    if (proj == 2) {
      // V: vt[bh][d][s], vectorize the 4 consecutive s of each acc vec
#pragma unroll
      for (int m = 0; m < MR; ++m) {
        int row0 = m0 + wr + m * 16 + l16 * 4;
        int b = row0 >> 11, s0 = row0 & 2047;
#pragma unroll
        for (int n = 0; n < 4; ++n) {
          int col = ((n0 & 1023) + wc) + n * 16 + l15;
          int h = col >> 6, d = col & 63;
          u16x4 pk = {f2b(acc[m][n][0] + bv[n]), f2b(acc[m][n][1] + bv[n]),
                      f2b(acc[m][n][2] + bv[n]), f2b(acc[m][n][3] + bv[n])};
          *(u16x4*)((u16*)out2 + ((size_t)((b * 16 + h) * 64 + d)) * 2048 + s0) = pk;
        }
      }
    } else {
      u16* dst = (u16*)(proj == 0 ? out0 : out1);
#pragma unroll
      for (int m = 0; m < MR; ++m)
#pragma unroll
        for (int i = 0; i < 4; ++i) {
          int row = m0 + wr + m * 16 + l16 * 4 + i;
          int b = row >> 11, s = row & 2047;
#pragma unroll
          for (int n = 0; n < 4; ++n) {
            int col = ((n0 & 1023) + wc) + n * 16 + l15;
            int h = col >> 6, d = col & 63;
            float v = acc[m][n][i] + bv[n];
            float partner = acc[m][n ^ 2][i] + bv[n ^ 2];
            float rot = (d < 32) ? -partner : partner;  // rotate_half
            float cs = cost[s * 32 + (d & 31)];
            float sn = sint[s * 32 + (d & 31)];
            dst[(((size_t)(b * 16 + h)) * 2048 + s) * 64 + d] = f2b(v * cs + rot * sn);
          }
        }
    }
  }
}

// ---------------- flash attention, causal, 64-row Q tiles ----------------
// qh,kh: [BH][S][HD] bf16; vt: [BH][HD][S] bf16; ctx out bf16 [B][S][H]
// grid (32, 32), 256 thr = 4 waves; wave owns 16 q rows. LDS 33.8 KB -> 4 blk/CU.
__global__ __launch_bounds__(256) void attn_kernel(
    const u16* __restrict__ qh, const u16* __restrict__ kh, const u16* __restrict__ vt,
    const float* __restrict__ amask, u16* __restrict__ ctx) {
  __shared__ u16 q_sh[64 * 64];   // swizzled
  __shared__ u16 k_sh[64 * 64];   // swizzled
  __shared__ u16 vt_sh[64 * 64];  // [d][kv], swizzled
  __shared__ u16 p_sh[64][72];    // padded (ds_write path)

  const int t = threadIdx.x;
  const int qt = 31 - (int)blockIdx.x;  // heavy-first
  const int bh = blockIdx.y;
  const int b = bh >> 4, h = bh & 15;
  const int q0 = qt * 64;
  const int w = t >> 6, lane = t & 63;
  const int l15 = lane & 15, l16 = lane >> 4;
  const int wq = w * 16;

  // stage Q (64x64) swizzled via global_load_lds
#pragma unroll
  for (int it = 0; it < 2; ++it) {
    int Lbase = it * 4096 + w * 1024;
    int L = Lbase + lane * 16;
    int r = L >> 7;
    int c = ((L ^ ((r & 7) << 4)) & 127) >> 1;
    gload16(qh + ((size_t)bh * 2048 + q0 + r) * 64 + c, (char*)q_sh + Lbase);
  }

  f32x4 o_acc[4] = {};
  f32x4 sa[4];
  float mrun[4], lrun[4];
#pragma unroll
  for (int i = 0; i < 4; ++i) { mrun[i] = -1e30f; lrun[i] = 0.f; }

  const int nkt = qt + 1;
  for (int kt = 0; kt < nkt; ++kt) {
    const int k0 = kt * 64;
    __syncthreads();
#pragma unroll
    for (int it = 0; it < 2; ++it) {
      int Lbase = it * 4096 + w * 1024;
      int L = Lbase + lane * 16;
      int r = L >> 7;
      int c = ((L ^ ((r & 7) << 4)) & 127) >> 1;
      gload16(kh + ((size_t)bh * 2048 + k0 + r) * 64 + c, (char*)k_sh + Lbase);
      gload16(vt + ((size_t)bh * 64 + r) * 2048 + k0 + c, (char*)vt_sh + Lbase);
    }
    __syncthreads();

    // S = Q @ K^T
#pragma unroll
    for (int n = 0; n < 4; ++n) sa[n] = f32x4{0.f, 0.f, 0.f, 0.f};
#pragma unroll
    for (int ks = 0; ks < 2; ++ks) {
      int row = wq + l15;
      int byt = ((row << 7) + ks * 64 + l16 * 16) ^ ((row & 7) << 4);
      u16x8 af = *(const u16x8*)((char*)q_sh + byt);
#pragma unroll
      for (int n = 0; n < 4; ++n) {
        int krow = n * 16 + l15;
        int kbyt = ((krow << 7) + ks * 64 + l16 * 16) ^ ((krow & 7) << 4);
        u16x8 bf = *(const u16x8*)((char*)k_sh + kbyt);
        sa[n] = mfma_bf16(af, bf, sa[n]);
      }
    }

    // online softmax; causal check only needed on the diagonal tile
    float mpen[4];
#pragma unroll
    for (int n = 0; n < 4; ++n)
      mpen[n] = (1.0f - amask[b * 2048 + k0 + n * 16 + l15]) * -1e4f;
    const bool last = (kt == qt);
#pragma unroll
    for (int i = 0; i < 4; ++i) {
      int qrow = q0 + wq + l16 * 4 + i;
      float vals[4];
      float tmax = -1e30f;
#pragma unroll
      for (int n = 0; n < 4; ++n) {
        float s = fmaf(sa[n][i], 0.125f, mpen[n]);
        if (last && (k0 + n * 16 + l15) > qrow) s = -1e10f;
        vals[n] = s;
        tmax = fmaxf(tmax, s);
      }
#pragma unroll
      for (int off = 1; off < 16; off <<= 1) tmax = fmaxf(tmax, __shfl_xor(tmax, off));
      float mnew = fmaxf(mrun[i], tmax);
      float alpha = __expf(mrun[i] - mnew);
      float psum = 0.f;
#pragma unroll
      for (int n = 0; n < 4; ++n) {
        float p = __expf(vals[n] - mnew);
        psum += p;
        p_sh[wq + l16 * 4 + i][n * 16 + l15] = f2b(p);
      }
#pragma unroll
      for (int off = 1; off < 16; off <<= 1) psum += __shfl_xor(psum, off);
      lrun[i] = lrun[i] * alpha + psum;
      mrun[i] = mnew;
#pragma unroll
      for (int n = 0; n < 4; ++n) o_acc[n][i] *= alpha;  // per-row rescale (R1 fix)
    }

    // O += P @ V  (P rows wave-private)
#pragma unroll
    for (int ks = 0; ks < 2; ++ks) {
      u16x8 pf = *(const u16x8*)&p_sh[wq + l15][ks * 32 + l16 * 8];
#pragma unroll
      for (int n = 0; n < 4; ++n) {
        int vrow = n * 16 + l15;
        int vbyt = ((vrow << 7) + ks * 64 + l16 * 16) ^ ((vrow & 7) << 4);
        u16x8 vf = *(const u16x8*)((char*)vt_sh + vbyt);
        o_acc[n] = mfma_bf16(pf, vf, o_acc[n]);
      }
    }
  }

  // ctx bf16 [B][S][H]
#pragma unroll
  for (int i = 0; i < 4; ++i) {
    float inv = 1.0f / lrun[i];
    int s = q0 + wq + l16 * 4 + i;
#pragma unroll
    for (int n = 0; n < 4; ++n) {
      int d = n * 16 + l15;
      ctx[((size_t)(b * 2048 + s)) * 1024 + h * 64 + d] = f2b(o_acc[n][i] * inv);
    }
  }
}

extern "C" void kernel_launch(void* const* d_in, const int* in_sizes, int n_in,
                              void* d_out, int out_size, void* d_ws, size_t ws_size,
                              hipStream_t stream) {
  const float* hs = (const float*)d_in[0];
  const float* amask = (const float*)d_in[1];
  const float* Wq = (const float*)d_in[2];
  const float* bq = (const float*)d_in[3];
  const float* Wk = (const float*)d_in[4];
  const float* bk = (const float*)d_in[5];
  const float* Wv = (const float*)d_in[6];
  const float* bv = (const float*)d_in[7];
  const float* Wo = (const float*)d_in[8];
  const float* bo = (const float*)d_in[9];
  float* out = (float*)d_out;

  // workspace layout (~40.6 MB)
  char* ws = (char*)d_ws;
  float* cost = (float*)ws;                        // 2048*32 f32
  float* sint = cost + 2048 * 32;
  u16* hsb = (u16*)(sint + 2048 * 32);             // 4096*1024 bf16 (reused as ctxb)
  u16* wqt = hsb + 4096 * 1024;                    // [wqt|wkt|wvt] contiguous = QKV Bt
  u16* wkt = wqt + 1024 * 1024;
  u16* wvt = wkt + 1024 * 1024;
  u16* wot = wvt + 1024 * 1024;
  u16* qh = wot + 1024 * 1024;                     // 32*2048*64 bf16 each
  u16* kh = qh + 32 * 2048 * 64;
  u16* vtg = kh + 32 * 2048 * 64;
  float* bqkv = (float*)(vtg + 32 * 2048 * 64);    // 3072 f32
  u16* ctxb = hsb;  // overlay: hsb dead after QKV-GEMM

  to_bf16_kernel<<<4096, 256, 0, stream>>>(hs, hsb, 1048576);
  dim3 tg(16, 16);
  transpose_w_kernel<<<tg, 256, 0, stream>>>(Wq, wqt);
  transpose_w_kernel<<<tg, 256, 0, stream>>>(Wk, wkt);
  transpose_w_kernel<<<tg, 256, 0, stream>>>(Wv, wvt);
  transpose_w_kernel<<<tg, 256, 0, stream>>>(Wo, wot);
  rope_tab_kernel<<<256, 256, 0, stream>>>(cost, sint);
  pack_bias_kernel<<<12, 256, 0, stream>>>(bq, bk, bv, bqkv);

  // fused QKV projection: N = 3072, 768 blocks
  gemm_bf16<4, 128><<<dim3(32, 24), 256, 0, stream>>>(
      hsb, wqt, bqkv, qh, kh, vtg, cost, sint, 4096, 3072, 1024);

  attn_kernel<<<dim3(32, 32), 256, 0, stream>>>(qh, kh, vtg, amask, ctxb);

  // output projection: BM=64 -> 512 blocks
  gemm_bf16<0, 64><<<dim3(64, 8), 256, 0, stream>>>(
      ctxb, wot, bo, out, nullptr, nullptr, nullptr, nullptr, 4096, 1024, 1024);
}